// Round 8
// baseline (209.780 us; speedup 1.0000x reference)
//
#include <hip/hip_runtime.h>

// GCN SpMM: out[i,d] = sum_{e: rows[e]==i} vals[e] * embeds[cols[e], d]
// rows sorted ascending. E=1.6M, N=100k, D=64.
//
// Round 15: XCD-slice partitioning -> L2-resident gathers.
// Evidence: spmm is bound by random gather service; ~2/3 of E x 128 B table
// reads miss the 4-MiB per-XCD L2 (12.8 MB table, uniform cols) and are
// served at the measured ~2.7 TB/s random-sector fabric rate (R12).
// Fix: split D=64 into 8 slices of 8 features (16 B bf16). Table stored
// slice-major [8][N] (1.6 MB/slice). Block handles (partition p, slice k)
// with k = blockIdx % 8 -> consecutive blocks round-robin across the 8 XCDs
// (m09/m157), so slice k's blocks land on one XCD and gather only from a
// 1.6-MB region that FITS its L2 -> random gathers become L2 hits.
// Cost: cols/vals read by all 8 slice-owners (8 x 12.8 MB = 102 MB) but
// streamed from LLC with NT hints (no L2 pollution). Net: ~40 -> ~25 us.
//   - per wave: 8 subgroups (nodes) x 8 edge-lanes; lane j does edges
//     lo+j, lo+j+8, ... gathering its edge's 16-B slice; unroll-4;
//     final 3-round __shfl_xor reduce per subgroup; NT out stores.
//   - prep: f32->bf16 convert TRANSPOSED to slice-major + CSR row_ptr
//     (merged, parallel; R14 structure).

constexpr int D = 64;

typedef float v4f __attribute__((ext_vector_type(4)));

__device__ __forceinline__ unsigned bf16rnd(unsigned u) {
    // round-to-nearest-even f32 -> bf16 (low 16 bits)
    return (u + 0x7FFFu + ((u >> 16) & 1u)) >> 16;
}
__device__ __forceinline__ float bflo(unsigned w) {
    union { unsigned u; float f; } x; x.u = w << 16; return x.f;
}
__device__ __forceinline__ float bfhi(unsigned w) {
    union { unsigned u; float f; } x; x.u = w & 0xFFFF0000u; return x.f;
}

// ---- prep (merged): f32 -> bf16 slice-major table + CSR row_ptr ---------
__global__ __launch_bounds__(256) void prep_kernel(
    const uint4* __restrict__ src,   // f32 embeds as uint4 (2 per 8-float group)
    uint4* __restrict__ dstT,        // bf16 slice-major [8][N], uint4 each
    int n8, int n_nodes,
    const int* __restrict__ rows, int* __restrict__ row_ptr,
    int n_edges, int cvt_blocks)
{
    if ((int)blockIdx.x < cvt_blocks) {
        int i = blockIdx.x * 256 + threadIdx.x;   // i = c*8 + k
        if (i >= n8) return;
        int c = i >> 3, k = i & 7;
        uint4 a = src[2 * i];                     // feats [8k, 8k+4) of node c
        uint4 b = src[2 * i + 1];                 // feats [8k+4, 8k+8)
        uint4 o;
        o.x = bf16rnd(a.x) | (bf16rnd(a.y) << 16);
        o.y = bf16rnd(a.z) | (bf16rnd(a.w) << 16);
        o.z = bf16rnd(b.x) | (bf16rnd(b.y) << 16);
        o.w = bf16rnd(b.z) | (bf16rnd(b.w) << 16);
        dstT[(size_t)k * n_nodes + c] = o;        // slice-major
    } else {
        int e = (blockIdx.x - cvt_blocks) * 256 + threadIdx.x;
        if (e >= n_edges) return;
        int r_cur  = rows[e];
        int r_prev = (e == 0) ? -1 : rows[e - 1];
        for (int r = r_prev + 1; r <= r_cur; ++r) row_ptr[r] = e;
        if (e == n_edges - 1)
            for (int r = r_cur + 1; r <= n_nodes; ++r) row_ptr[r] = n_edges;
    }
}

// ---- spmm: slice-partitioned, edge-parallel subgroups -------------------
__global__ __launch_bounds__(256, 4) void spmm_slice_kernel(
    const int* __restrict__ row_ptr,
    const int* __restrict__ cols,
    const float* __restrict__ vals,
    const uint4* __restrict__ ebfT,       // bf16 slice-major [8][N]
    float4* __restrict__ out4,            // [N,16] float4 view
    int n_nodes)
{
    constexpr int CHUNK = 256;            // edges staged per wave per pass
    __shared__ int   s_cols[4][CHUNK];    // 4 waves/block, wave-private
    __shared__ float s_vals[4][CHUNK];

    const int lane = threadIdx.x & 63;
    const int j    = lane & 7;            // edge-lane within subgroup (0..7)
    const int s    = lane >> 3;           // subgroup (node) within wave (0..7)
    const int w    = threadIdx.x >> 6;    // wave within block
    const int k    = blockIdx.x & 7;      // feature slice == XCD (round-robin)
    const int p    = blockIdx.x >> 3;     // node partition (32 nodes)
    const int nb   = p * 32 + w * 8;      // this wave's node octet
    if (nb >= n_nodes) return;

    const uint4* __restrict__ slice = ebfT + (size_t)k * n_nodes;  // 1.6 MB

    const int nbhi  = (nb + 8 <= n_nodes) ? nb + 8 : n_nodes;
    const int wbase = row_ptr[nb];        // wave's contiguous edge span
    const int wend  = row_ptr[nbhi];
    const int node  = nb + s;
    const bool live = (node < n_nodes);
    const int lo    = live ? row_ptr[node]     : wend;
    const int hi    = live ? row_ptr[node + 1] : wend;

    float4 acc0 = make_float4(0.f, 0.f, 0.f, 0.f);
    float4 acc1 = make_float4(0.f, 0.f, 0.f, 0.f);

    for (int cbase = wbase; cbase < wend; cbase += CHUNK) {
        // cooperative, coalesced staging; NT (streams, keep L2 for the slice)
        #pragma unroll
        for (int q = 0; q < CHUNK; q += 64) {
            if (cbase + q >= wend) break;         // wave-uniform early out
            int idx = cbase + q + lane;
            if (idx < wend) {
                s_cols[w][q + lane] = __builtin_nontemporal_load(&cols[idx]);
                s_vals[w][q + lane] = __builtin_nontemporal_load(&vals[idx]);
            }
        }
        __builtin_amdgcn_wave_barrier();  // pin ds_writes before ds_reads

        const int cend = (cbase + CHUNK < wend) ? cbase + CHUNK : wend;
        const int e0 = (lo > cbase) ? lo : cbase; // node's slice of this chunk
        const int e1 = (hi < cend)  ? hi : cend;

        // lane j walks edges e0+j, e0+j+8, ... ; unroll-4 (32 edges/subgroup)
        for (int e = e0 + j; e < e1; e += 32) {
            const int last = e1 - 1;
            int ia = e;
            int ib = (e + 8  <= last) ? e + 8  : last;
            int ic = (e + 16 <= last) ? e + 16 : last;
            int id = (e + 24 <= last) ? e + 24 : last;

            int ca = s_cols[w][ia - cbase];
            int cb = s_cols[w][ib - cbase];
            int cc = s_cols[w][ic - cbase];
            int cd = s_cols[w][id - cbase];

            float va = s_vals[w][ia - cbase];
            float vb = (e + 8  < e1) ? s_vals[w][ib - cbase] : 0.f;
            float vc = (e + 16 < e1) ? s_vals[w][ic - cbase] : 0.f;
            float vd = (e + 24 < e1) ? s_vals[w][id - cbase] : 0.f;

            // 4 independent 16-B gathers per lane; 64 addresses per instr
            uint4 ma = slice[ca];
            uint4 mb = slice[cb];
            uint4 mc = slice[cc];
            uint4 md = slice[cd];

            acc0.x += va * bflo(ma.x); acc0.y += va * bfhi(ma.x);
            acc0.z += va * bflo(ma.y); acc0.w += va * bfhi(ma.y);
            acc1.x += va * bflo(ma.z); acc1.y += va * bfhi(ma.z);
            acc1.z += va * bflo(ma.w); acc1.w += va * bfhi(ma.w);

            acc0.x += vb * bflo(mb.x); acc0.y += vb * bfhi(mb.x);
            acc0.z += vb * bflo(mb.y); acc0.w += vb * bfhi(mb.y);
            acc1.x += vb * bflo(mb.z); acc1.y += vb * bfhi(mb.z);
            acc1.z += vb * bflo(mb.w); acc1.w += vb * bfhi(mb.w);

            acc0.x += vc * bflo(mc.x); acc0.y += vc * bfhi(mc.x);
            acc0.z += vc * bflo(mc.y); acc0.w += vc * bfhi(mc.y);
            acc1.x += vc * bflo(mc.z); acc1.y += vc * bfhi(mc.z);
            acc1.z += vc * bflo(mc.w); acc1.w += vc * bfhi(mc.w);

            acc0.x += vd * bflo(md.x); acc0.y += vd * bfhi(md.x);
            acc0.z += vd * bflo(md.y); acc0.w += vd * bfhi(md.y);
            acc1.x += vd * bflo(md.z); acc1.y += vd * bfhi(md.z);
            acc1.z += vd * bflo(md.w); acc1.w += vd * bfhi(md.w);
        }
        __builtin_amdgcn_wave_barrier();  // next chunk's writes after reads
    }

    // reduce the 8 edge-lanes of each subgroup (xor 1,2,4 stays in subgroup)
    #pragma unroll
    for (int m = 1; m <= 4; m <<= 1) {
        acc0.x += __shfl_xor(acc0.x, m, 64);
        acc0.y += __shfl_xor(acc0.y, m, 64);
        acc0.z += __shfl_xor(acc0.z, m, 64);
        acc0.w += __shfl_xor(acc0.w, m, 64);
        acc1.x += __shfl_xor(acc1.x, m, 64);
        acc1.y += __shfl_xor(acc1.y, m, 64);
        acc1.z += __shfl_xor(acc1.z, m, 64);
        acc1.w += __shfl_xor(acc1.w, m, 64);
    }

    if (live) {
        // node's out slice = 8 f32 = 32 B at float offset node*64 + k*8
        long ob = (long)node * 16 + k * 2;
        if (j == 0)
            __builtin_nontemporal_store(*(const v4f*)&acc0, (v4f*)&out4[ob]);
        if (j == 1)
            __builtin_nontemporal_store(*(const v4f*)&acc1, (v4f*)&out4[ob + 1]);
    }
}

// ------------------------------------------------------------------ host ---
extern "C" void kernel_launch(void* const* d_in, const int* in_sizes, int n_in,
                              void* d_out, int out_size, void* d_ws, size_t ws_size,
                              hipStream_t stream) {
    const int*   rows   = (const int*)d_in[0];
    const int*   cols   = (const int*)d_in[1];
    const float* vals   = (const float*)d_in[2];
    const float* embeds = (const float*)d_in[3];
    float4*      out4   = (float4*)d_out;

    const int n_edges = in_sizes[0];
    const int n_nodes = out_size / D;                 // 100000
    const int n_feat  = in_sizes[3];                  // 6,400,000

    char*  ws        = (char*)d_ws;
    uint4* ebfT      = (uint4*)ws;                    // 12.8 MB slice-major
    int*   row_ptr   = (int*)(ws + (size_t)n_feat * 2);

    // 1) merged prep: transposed bf16 table + CSR row pointers
    int n8         = n_feat / 8;                      // 800,000 groups
    int cvt_blocks = (n8 + 255) / 256;                // 3125
    int row_blocks = (n_edges + 255) / 256;           // 6250
    prep_kernel<<<cvt_blocks + row_blocks, 256, 0, stream>>>(
        (const uint4*)embeds, ebfT, n8, n_nodes,
        rows, row_ptr, n_edges, cvt_blocks);

    // 2) slice-partitioned SpMM: block = (partition of 32 nodes, slice k)
    //    k = blockIdx % 8 keeps each slice on one XCD (round-robin dispatch)
    int parts  = (n_nodes + 31) / 32;                 // 3125
    int blocks = parts * 8;                           // 25000
    spmm_slice_kernel<<<blocks, 256, 0, stream>>>(
        row_ptr, cols, vals, ebfT, out4, n_nodes);
}

// Round 9
// 120.778 us; speedup vs baseline: 1.7369x; 1.7369x over previous
//
#include <hip/hip_runtime.h>

// GCN SpMM: out[i,d] = sum_{e: rows[e]==i} vals[e] * embeds[cols[e], d]
// rows sorted ascending. E=1.6M, N=100k, D=64.
//
// Round 16: REVERT to Round 14 (best measured: 119.75 us).
// R15 (XCD slice-partitioning) post-mortem closed the last design branch:
//   - 16-B random gather granularity = 4x sector waste through L1/L2
//     (64 distinct 64-B sectors/instr, 16 B useful each) -> 3x slower
//     despite L2-resident slices.
//   - 8x cols/vals staging replication added ~100 MB LLC stream traffic.
// Constraints now established by measurement:
//   (a) distinct random addresses must be >=64 B (full sector);
//   (b) edge data must be read exactly once;
//   (c) bf16 is the accuracy-safe minimum row size (128 B).
// (a)+(b)+(c) force exactly this geometry. Remaining budget:
//   72 us fixed harness overhead (poison fills + graph gaps; invariant
//   across R12/R13/R14) + prep ~7.5 us (45 MB compulsory stream) +
//   spmm ~40 us (~110-140 MB L2-miss gathers at the measured 2.7-2.8 TB/s
//   random-sector service rate). Both controllable terms at their floors.
//
// Structure:
//   1) prep (merged): f32->bf16 table (12.8 MB in d_ws) + CSR row_ptr.
//   2) spmm: 8-lane subgroups (8 nodes/wave), lane t owns 16 B of the
//      128-B bf16 row (1 gather instr = 8 rows, full sectors); wave-private
//      LDS staging of cols/vals (NT); unroll-8 gather pipeline; NT stores.

constexpr int D = 64;

typedef float v4f __attribute__((ext_vector_type(4)));

__device__ __forceinline__ unsigned bf16rnd(unsigned u) {
    // round-to-nearest-even f32 -> bf16 (low 16 bits)
    return (u + 0x7FFFu + ((u >> 16) & 1u)) >> 16;
}
__device__ __forceinline__ float bflo(unsigned w) {
    union { unsigned u; float f; } x; x.u = w << 16; return x.f;
}
__device__ __forceinline__ float bfhi(unsigned w) {
    union { unsigned u; float f; } x; x.u = w & 0xFFFF0000u; return x.f;
}

// ---- prep (merged): f32->bf16 table + CSR row_ptr -----------------------
__global__ __launch_bounds__(256) void prep_kernel(
    const uint4* __restrict__ src,   // f32 embeds as uint4 (2 per 8-float group)
    uint4* __restrict__ dst,         // bf16 table as uint4 (8 bf16)
    int n8,
    const int* __restrict__ rows, int* __restrict__ row_ptr,
    int n_edges, int n_nodes, int cvt_blocks)
{
    if ((int)blockIdx.x < cvt_blocks) {
        int i = blockIdx.x * 256 + threadIdx.x;
        if (i >= n8) return;
        uint4 a = src[2 * i];
        uint4 b = src[2 * i + 1];
        uint4 o;
        o.x = bf16rnd(a.x) | (bf16rnd(a.y) << 16);
        o.y = bf16rnd(a.z) | (bf16rnd(a.w) << 16);
        o.z = bf16rnd(b.x) | (bf16rnd(b.y) << 16);
        o.w = bf16rnd(b.z) | (bf16rnd(b.w) << 16);
        dst[i] = o;
    } else {
        int e = (blockIdx.x - cvt_blocks) * 256 + threadIdx.x;
        if (e >= n_edges) return;
        int r_cur  = rows[e];
        int r_prev = (e == 0) ? -1 : rows[e - 1];
        for (int r = r_prev + 1; r <= r_cur; ++r) row_ptr[r] = e;
        if (e == n_edges - 1)
            for (int r = r_cur + 1; r <= n_nodes; ++r) row_ptr[r] = n_edges;
    }
}

// ---- spmm: node-centric, bf16 gathers, row_ptr bounds -------------------
__global__ __launch_bounds__(256, 4) void spmm_node_kernel(
    const int* __restrict__ row_ptr,
    const int* __restrict__ cols,
    const float* __restrict__ vals,
    const uint4* __restrict__ ebf4,       // bf16 [N,64]: row = 8 uint4
    float4* __restrict__ out4,            // [N,16] float4 view
    int n_nodes)
{
    constexpr int CHUNK = 256;            // edges staged per wave per pass
    __shared__ int   s_cols[4][CHUNK];    // 4 waves/block, wave-private
    __shared__ float s_vals[4][CHUNK];

    const int lane = threadIdx.x & 63;
    const int t    = lane & 7;            // 16B chunk within row (0..7)
    const int s    = lane >> 3;           // subgroup (node) within wave (0..7)
    const int w    = threadIdx.x >> 6;    // wave within block
    const int wave = blockIdx.x * 4 + w;
    const int node = wave * 8 + s;
    if (node >= n_nodes) return;

    const int nb    = wave * 8;
    const int nbhi  = (nb + 8 <= n_nodes) ? nb + 8 : n_nodes;
    const int wbase = row_ptr[nb];        // wave's contiguous edge span
    const int wend  = row_ptr[nbhi];
    const int lo    = row_ptr[node];
    const int hi    = row_ptr[node + 1];

    float4 acc0 = make_float4(0.f, 0.f, 0.f, 0.f);
    float4 acc1 = make_float4(0.f, 0.f, 0.f, 0.f);

    for (int cbase = wbase; cbase < wend; cbase += CHUNK) {
        // cooperative, coalesced staging; NT (touch-once streams, keep L2
        // for the 16x-reused table)
        #pragma unroll
        for (int j = 0; j < CHUNK; j += 64) {
            if (cbase + j >= wend) break;         // wave-uniform early out
            int idx = cbase + j + lane;
            if (idx < wend) {
                s_cols[w][j + lane] = __builtin_nontemporal_load(&cols[idx]);
                s_vals[w][j + lane] = __builtin_nontemporal_load(&vals[idx]);
            }
        }
        __builtin_amdgcn_wave_barrier();  // pin ds_writes before ds_reads

        const int cend = (cbase + CHUNK < wend) ? cbase + CHUNK : wend;
        int e0 = (lo > cbase) ? lo : cbase;       // this node's slice of chunk
        int e1 = (hi < cend)  ? hi : cend;

        for (int e = e0; e < e1; e += 8) {
            const int last = e1 - 1;
            int i0 = e - cbase;
            int i1 = ((e + 1 <= last) ? e + 1 : last) - cbase;
            int i2 = ((e + 2 <= last) ? e + 2 : last) - cbase;
            int i3 = ((e + 3 <= last) ? e + 3 : last) - cbase;
            int i4 = ((e + 4 <= last) ? e + 4 : last) - cbase;
            int i5 = ((e + 5 <= last) ? e + 5 : last) - cbase;
            int i6 = ((e + 6 <= last) ? e + 6 : last) - cbase;
            int i7 = ((e + 7 <= last) ? e + 7 : last) - cbase;

            int c0 = s_cols[w][i0], c1 = s_cols[w][i1];
            int c2 = s_cols[w][i2], c3 = s_cols[w][i3];
            int c4 = s_cols[w][i4], c5 = s_cols[w][i5];
            int c6 = s_cols[w][i6], c7 = s_cols[w][i7];

            float v0 = s_vals[w][i0];
            float v1 = (e + 1 < e1) ? s_vals[w][i1] : 0.f;
            float v2 = (e + 2 < e1) ? s_vals[w][i2] : 0.f;
            float v3 = (e + 3 < e1) ? s_vals[w][i3] : 0.f;
            float v4 = (e + 4 < e1) ? s_vals[w][i4] : 0.f;
            float v5 = (e + 5 < e1) ? s_vals[w][i5] : 0.f;
            float v6 = (e + 6 < e1) ? s_vals[w][i6] : 0.f;
            float v7 = (e + 7 < e1) ? s_vals[w][i7] : 0.f;

            // 8 independent dwordx4 gathers in flight; each covers 8 rows
            uint4 m0 = ebf4[c0 * 8 + t];
            uint4 m1 = ebf4[c1 * 8 + t];
            uint4 m2 = ebf4[c2 * 8 + t];
            uint4 m3 = ebf4[c3 * 8 + t];
            uint4 m4 = ebf4[c4 * 8 + t];
            uint4 m5 = ebf4[c5 * 8 + t];
            uint4 m6 = ebf4[c6 * 8 + t];
            uint4 m7 = ebf4[c7 * 8 + t];

            acc0.x += v0 * bflo(m0.x); acc0.y += v0 * bfhi(m0.x);
            acc0.z += v0 * bflo(m0.y); acc0.w += v0 * bfhi(m0.y);
            acc1.x += v0 * bflo(m0.z); acc1.y += v0 * bfhi(m0.z);
            acc1.z += v0 * bflo(m0.w); acc1.w += v0 * bfhi(m0.w);

            acc0.x += v1 * bflo(m1.x); acc0.y += v1 * bfhi(m1.x);
            acc0.z += v1 * bflo(m1.y); acc0.w += v1 * bfhi(m1.y);
            acc1.x += v1 * bflo(m1.z); acc1.y += v1 * bfhi(m1.z);
            acc1.z += v1 * bflo(m1.w); acc1.w += v1 * bfhi(m1.w);

            acc0.x += v2 * bflo(m2.x); acc0.y += v2 * bfhi(m2.x);
            acc0.z += v2 * bflo(m2.y); acc0.w += v2 * bfhi(m2.y);
            acc1.x += v2 * bflo(m2.z); acc1.y += v2 * bfhi(m2.z);
            acc1.z += v2 * bflo(m2.w); acc1.w += v2 * bfhi(m2.w);

            acc0.x += v3 * bflo(m3.x); acc0.y += v3 * bfhi(m3.x);
            acc0.z += v3 * bflo(m3.y); acc0.w += v3 * bfhi(m3.y);
            acc1.x += v3 * bflo(m3.z); acc1.y += v3 * bfhi(m3.z);
            acc1.z += v3 * bflo(m3.w); acc1.w += v3 * bfhi(m3.w);

            acc0.x += v4 * bflo(m4.x); acc0.y += v4 * bfhi(m4.x);
            acc0.z += v4 * bflo(m4.y); acc0.w += v4 * bfhi(m4.y);
            acc1.x += v4 * bflo(m4.z); acc1.y += v4 * bfhi(m4.z);
            acc1.z += v4 * bflo(m4.w); acc1.w += v4 * bfhi(m4.w);

            acc0.x += v5 * bflo(m5.x); acc0.y += v5 * bfhi(m5.x);
            acc0.z += v5 * bflo(m5.y); acc0.w += v5 * bfhi(m5.y);
            acc1.x += v5 * bflo(m5.z); acc1.y += v5 * bfhi(m5.z);
            acc1.z += v5 * bflo(m5.w); acc1.w += v5 * bfhi(m5.w);

            acc0.x += v6 * bflo(m6.x); acc0.y += v6 * bfhi(m6.x);
            acc0.z += v6 * bflo(m6.y); acc0.w += v6 * bfhi(m6.y);
            acc1.x += v6 * bflo(m6.z); acc1.y += v6 * bfhi(m6.z);
            acc1.z += v6 * bflo(m6.w); acc1.w += v6 * bfhi(m6.w);

            acc0.x += v7 * bflo(m7.x); acc0.y += v7 * bfhi(m7.x);
            acc0.z += v7 * bflo(m7.y); acc0.w += v7 * bfhi(m7.y);
            acc1.x += v7 * bflo(m7.z); acc1.y += v7 * bfhi(m7.z);
            acc1.z += v7 * bflo(m7.w); acc1.w += v7 * bfhi(m7.w);
        }
        __builtin_amdgcn_wave_barrier();  // next chunk's writes after reads
    }

    // NT stores: out is touch-once, keep it out of L2
    long ob = (long)node * 16 + 2 * t;    // features [8t, 8t+8)
    __builtin_nontemporal_store(*(const v4f*)&acc0, (v4f*)&out4[ob]);
    __builtin_nontemporal_store(*(const v4f*)&acc1, (v4f*)&out4[ob + 1]);
}

// ------------------------------------------------------------------ host ---
extern "C" void kernel_launch(void* const* d_in, const int* in_sizes, int n_in,
                              void* d_out, int out_size, void* d_ws, size_t ws_size,
                              hipStream_t stream) {
    const int*   rows   = (const int*)d_in[0];
    const int*   cols   = (const int*)d_in[1];
    const float* vals   = (const float*)d_in[2];
    const float* embeds = (const float*)d_in[3];
    float4*      out4   = (float4*)d_out;

    const int n_edges = in_sizes[0];
    const int n_nodes = out_size / D;                 // 100000
    const int n_feat  = in_sizes[3];                  // 6,400,000

    char*  ws        = (char*)d_ws;
    uint4* ebf_table = (uint4*)ws;                    // 12.8 MB bf16 table
    int*   row_ptr   = (int*)(ws + (size_t)n_feat * 2);

    // 1) merged prep: f32->bf16 table + CSR row pointers
    int n8         = n_feat / 8;                      // 800,000 groups
    int cvt_blocks = (n8 + 255) / 256;                // 3125
    int row_blocks = (n_edges + 255) / 256;           // 6250
    prep_kernel<<<cvt_blocks + row_blocks, 256, 0, stream>>>(
        (const uint4*)embeds, ebf_table, n8,
        rows, row_ptr, n_edges, n_nodes, cvt_blocks);

    // 2) node-centric SpMM: 8 nodes/wave, 4 waves/block
    int waves  = (n_nodes + 7) / 8;                   // 12500
    int blocks = (waves + 3) / 4;                     // 3125
    spmm_node_kernel<<<blocks, 256, 0, stream>>>(
        row_ptr, cols, vals, ebf_table, out4, n_nodes);
}